// Round 13
// baseline (4427.593 us; speedup 1.0000x reference)
//
#include <hip/hip_runtime.h>
#include <math.h>

// CTRNN + adaptive DOPRI5 (B=2048, N=1024). Round 13 = r9 persistence +
// r12 GEMM. Persistent kernel, 256 blocks x 512 thr, block = 8 complete
// batch rows (zero intra-step inter-block communication; act in block-local
// LDS ping-pong). ODE state entirely register-resident for the whole run.
// One packed-flag exchange per step (r9-validated); controller redundant
// and uniform in every block; dead steps cost nothing (uniform break).
// GEMM: fragment-contiguous Wf stream + per-CU K-phase rotation (r12) +
// 3-set rotating register prefetch under __launch_bounds__(512,1).

typedef float f4 __attribute__((ext_vector_type(4)));
typedef float f32x4 __attribute__((ext_vector_type(4)));
typedef _Float16 half8v __attribute__((ext_vector_type(8)));
typedef _Float16 half2v __attribute__((ext_vector_type(2)));
typedef unsigned long long u64;

#define NBLK 256
#define NTHR 512

#define E1c (71.0f / 57600.0f)
#define E3c (-71.0f / 16695.0f)
#define E4c (71.0f / 1920.0f)
#define E5c (-17253.0f / 339200.0f)
#define E6c (22.0f / 525.0f)
#define E7c (-1.0f / 40.0f)

#define ALD64(p) __hip_atomic_load((p), __ATOMIC_ACQUIRE, __HIP_MEMORY_SCOPE_AGENT)
#define AST64(p, v) __hip_atomic_store((p), (v), __ATOMIC_RELEASE, __HIP_MEMORY_SCOPE_AGENT)

__global__ void k_zero(u64* pk) {
  int i = blockIdx.x * blockDim.x + threadIdx.x;
  if (i < 2048) pk[i] = 0ull;
}

__device__ __forceinline__ float ftanh(float x) {
  x = fminf(fmaxf(x, -9.0f), 9.0f);
  float e = __expf(2.0f * x);
  return (e - 1.0f) / (e + 1.0f);
}

// Wf[((ct16*32 + kb)*64 + l)*8 + j] = W[ct16*16 + (l&15)][kb*32 + (l>>4)*8 + j]
__global__ void k_prep(const float* __restrict__ W, _Float16* __restrict__ Wf) {
  int i = blockIdx.x * blockDim.x + threadIdx.x;   // 0..131071
  int l = i & 63, kb = (i >> 6) & 31, ct = i >> 11;
  const float* src = W + (size_t)(ct * 16 + (l & 15)) * 1024 + kb * 32 + (l >> 4) * 8;
  half8v o;
#pragma unroll
  for (int j = 0; j < 8; ++j) o[j] = (_Float16)src[j];
  *(half8v*)(Wf + ((size_t)i << 3)) = o;
}

// acc[8] = rec fragments for this wave's 8 col-tiles. A from LDS act
// (row = l&7, XOR-swizzled granules); B from fragment-contiguous Wf with
// per-CU K-phase rotation + 3-set rotating register prefetch (2 in flight).
__device__ __forceinline__ void gemm8(const char* actB,
                                      const _Float16* __restrict__ wfb,
                                      int l, int rot, f32x4 acc[8]) {
#pragma unroll
  for (int ct = 0; ct < 8; ++ct)
#pragma unroll
    for (int q = 0; q < 4; ++q) acc[ct][q] = 0.0f;
  const int r = l & 7, lk = l >> 4;
  const char* arow = actB + r * 2048;
  half8v bs[3][8];
#define LDB(si, kbi)                                                      \
  {                                                                       \
    const int kbv = (kbi) & 31;                                           \
    _Pragma("unroll") for (int ct = 0; ct < 8; ++ct)                      \
        bs[si][ct] = *(const half8v*)(wfb + (((ct << 5) + kbv) << 9));    \
  }
  LDB(0, rot);
  LDB(1, rot + 1);
#pragma unroll
  for (int it = 0; it < 32; ++it) {
    if (it + 2 < 32) LDB((it + 2) % 3, it + 2 + rot);
    const int kbv = (it + rot) & 31;
    half8v a = *(const half8v*)(arow + ((((kbv << 2) | lk) ^ r) << 4));
#pragma unroll
    for (int ct = 0; ct < 8; ++ct)
      acc[ct] = __builtin_amdgcn_mfma_f32_16x16x32_f16(a, bs[it % 3][ct], acc[ct], 0, 0, 0);
  }
#undef LDB
}

// e = ci*4 + q. Thread owns rows ((l>>4)&1)*4+q, cols wv*128+((l>>5)*4+ci)*16+(l&15).
template <int S>
__device__ __forceinline__ void stage_epi(
    const f32x4 acc[8], float h,
    float* y, float* ys, const half2v* dh,
    half2v* k1h, half2v* k2h, half2v* k3h, half2v* k4h, half2v* k5h, half2v* eh,
    const float* itau4, const float* bias4,
    char* actOut, int wv, int l, float* errAcc) {
  f32x4 sa[4];
  if (l >= 32) { sa[0] = acc[4]; sa[1] = acc[5]; sa[2] = acc[6]; sa[3] = acc[7]; }
  else         { sa[0] = acc[0]; sa[1] = acc[1]; sa[2] = acc[2]; sa[3] = acc[3]; }
#pragma unroll
  for (int ci = 0; ci < 4; ++ci) {
#pragma unroll
    for (int q = 0; q < 4; ++q) {
      const int e = ci * 4 + q;
      float yv = y[e];
      float ks;
      if constexpr (S == 1) {
        ks = (float)k1h[e >> 1][e & 1];
      } else {
        ks = itau4[ci] * ((float)dh[e >> 1][e & 1] + sa[ci][q] - ys[e]);
      }
      float nys;
      if constexpr (S == 1) {
        eh[e >> 1][e & 1] = (_Float16)(E1c * ks);
        nys = yv + h * (0.2f * ks);
      } else if constexpr (S == 2) {
        k2h[e >> 1][e & 1] = (_Float16)ks;
        float k1 = (float)k1h[e >> 1][e & 1];
        nys = yv + h * ((3.0f / 40.0f) * k1 + (9.0f / 40.0f) * ks);
      } else if constexpr (S == 3) {
        k3h[e >> 1][e & 1] = (_Float16)ks;
        eh[e >> 1][e & 1] = (_Float16)((float)eh[e >> 1][e & 1] + E3c * ks);
        float k1 = (float)k1h[e >> 1][e & 1], k2 = (float)k2h[e >> 1][e & 1];
        nys = yv + h * ((44.0f / 45.0f) * k1 + (-56.0f / 15.0f) * k2 + (32.0f / 9.0f) * ks);
      } else if constexpr (S == 4) {
        k4h[e >> 1][e & 1] = (_Float16)ks;
        eh[e >> 1][e & 1] = (_Float16)((float)eh[e >> 1][e & 1] + E4c * ks);
        float k1 = (float)k1h[e >> 1][e & 1], k2 = (float)k2h[e >> 1][e & 1];
        float k3 = (float)k3h[e >> 1][e & 1];
        nys = yv + h * ((19372.0f / 6561.0f) * k1 + (-25360.0f / 2187.0f) * k2 +
                        (64448.0f / 6561.0f) * k3 + (-212.0f / 729.0f) * ks);
      } else if constexpr (S == 5) {
        k5h[e >> 1][e & 1] = (_Float16)ks;
        eh[e >> 1][e & 1] = (_Float16)((float)eh[e >> 1][e & 1] + E5c * ks);
        float k1 = (float)k1h[e >> 1][e & 1], k2 = (float)k2h[e >> 1][e & 1];
        float k3 = (float)k3h[e >> 1][e & 1], k4 = (float)k4h[e >> 1][e & 1];
        nys = yv + h * ((9017.0f / 3168.0f) * k1 + (-355.0f / 33.0f) * k2 +
                        (46732.0f / 5247.0f) * k3 + (49.0f / 176.0f) * k4 +
                        (-5103.0f / 18656.0f) * ks);
      } else if constexpr (S == 6) {
        eh[e >> 1][e & 1] = (_Float16)((float)eh[e >> 1][e & 1] + E6c * ks);
        float k1 = (float)k1h[e >> 1][e & 1];
        float k3 = (float)k3h[e >> 1][e & 1], k4 = (float)k4h[e >> 1][e & 1];
        float k5 = (float)k5h[e >> 1][e & 1];
        nys = yv + h * ((35.0f / 384.0f) * k1 + (500.0f / 1113.0f) * k3 +
                        (125.0f / 192.0f) * k4 + (-2187.0f / 6784.0f) * k5 +
                        (11.0f / 84.0f) * ks);
      } else {  // S == 7: k7 -> k2h slot (dead after S5); error norm
        k2h[e >> 1][e & 1] = (_Float16)ks;
        float ev = h * ((float)eh[e >> 1][e & 1] + E7c * ks);
        float sc = 1e-6f + 1e-3f * fmaxf(fabsf(yv), fabsf(ys[e]));
        float r = ev / sc;
        *errAcc += r * r;
        nys = 0.0f;
      }
      if constexpr (S <= 6) {
        ys[e] = nys;
        float av = ftanh(nys + bias4[ci]);
        int row = ((l >> 4) & 1) * 4 + q;
        int col = wv * 128 + ((l >> 5) * 4 + ci) * 16 + (l & 15);
        *(_Float16*)(actOut + row * 2048 + (((col >> 3) ^ row) << 4) + (col & 7) * 2) =
            (_Float16)av;
      }
    }
  }
}

__global__ __launch_bounds__(NTHR, 1) void k_ode(
    const float* __restrict__ inp, const float* __restrict__ prev,
    const float* __restrict__ tau, const float* __restrict__ iw,
    const float* __restrict__ bias, const _Float16* __restrict__ Wf,
    float* __restrict__ out, u64* __restrict__ pk) {
  __shared__ _Float16 actL[2][8][1024];   // 32 KB ping-pong act
  __shared__ float sm[256];
  __shared__ float wsum[8];
  __shared__ float bc;

  const int tid = (int)threadIdx.x, bid = (int)blockIdx.x;
  const int l = tid & 63, wv = tid >> 6;
  const int lr16 = l & 15;
  const int rbase = bid * 8;
  const int rot = (bid >> 3) & 31;     // per-CU K phase (32 CUs/XCD distinct)
  char* A0 = (char*)&actL[0][0][0];
  char* A1 = (char*)&actL[1][0][0];
  const _Float16* wfb = Wf + ((size_t)wv << 17) + (l << 3);

  // --- state init (registers for the whole run) + act1 -> A1 ---
  float y[16], ysr[16];
  half2v dh[8], k1h[8], k2h[8], k3h[8], k4h[8], k5h[8], eh[8];
  float itau4[4], bias4[4];
#pragma unroll
  for (int ci = 0; ci < 4; ++ci) {
    int col = wv * 128 + ((l >> 5) * 4 + ci) * 16 + lr16;
    itau4[ci] = 1.0f / tau[col];
    bias4[ci] = bias[col];
  }
#pragma unroll
  for (int ci = 0; ci < 4; ++ci)
#pragma unroll
    for (int q = 0; q < 4; ++q) {
      const int e = ci * 4 + q;
      int row = ((l >> 4) & 1) * 4 + q;
      int col = wv * 128 + ((l >> 5) * 4 + ci) * 16 + lr16;
      size_t off = (size_t)(rbase + row) * 1024 + col;
      float yv = prev[off];
      y[e] = yv;
      ysr[e] = yv;
      dh[e >> 1][e & 1] = (_Float16)(inp[off] * iw[col]);
      float av = ftanh(yv + bias4[ci]);
      *(_Float16*)(A1 + row * 2048 + (((col >> 3) ^ row) << 4) + (col & 7) * 2) =
          (_Float16)av;
    }
  __syncthreads();

  // initial k1 = itau*(drive + W@act1 - y)   (Wf visible via kernel boundary)
  f32x4 acc[8];
  gemm8(A1, wfb, l, rot, acc);
  {
    f32x4 sa[4];
    if (l >= 32) { sa[0] = acc[4]; sa[1] = acc[5]; sa[2] = acc[6]; sa[3] = acc[7]; }
    else         { sa[0] = acc[0]; sa[1] = acc[1]; sa[2] = acc[2]; sa[3] = acc[3]; }
#pragma unroll
    for (int ci = 0; ci < 4; ++ci)
#pragma unroll
      for (int q = 0; q < 4; ++q) {
        const int e = ci * 4 + q;
        k1h[e >> 1][e & 1] =
            (_Float16)(itau4[ci] * ((float)dh[e >> 1][e & 1] + sa[ci][q] - y[e]));
      }
  }
  __syncthreads();

  float t = 0.0f, dtv = 0.1f;
#pragma unroll 1
  for (int s = 0; s < 40; ++s) {
    if (t >= 1.0f - 1e-7f) break;
    const float h = fminf(dtv, 1.0f - t);

    stage_epi<1>(acc, h, y, ysr, dh, k1h, k2h, k3h, k4h, k5h, eh, itau4, bias4,
                 A0, wv, l, nullptr);
    __syncthreads();
    gemm8(A0, wfb, l, rot, acc);
    stage_epi<2>(acc, h, y, ysr, dh, k1h, k2h, k3h, k4h, k5h, eh, itau4, bias4,
                 A1, wv, l, nullptr);
    __syncthreads();
    gemm8(A1, wfb, l, rot, acc);
    stage_epi<3>(acc, h, y, ysr, dh, k1h, k2h, k3h, k4h, k5h, eh, itau4, bias4,
                 A0, wv, l, nullptr);
    __syncthreads();
    gemm8(A0, wfb, l, rot, acc);
    stage_epi<4>(acc, h, y, ysr, dh, k1h, k2h, k3h, k4h, k5h, eh, itau4, bias4,
                 A1, wv, l, nullptr);
    __syncthreads();
    gemm8(A1, wfb, l, rot, acc);
    stage_epi<5>(acc, h, y, ysr, dh, k1h, k2h, k3h, k4h, k5h, eh, itau4, bias4,
                 A0, wv, l, nullptr);
    __syncthreads();
    gemm8(A0, wfb, l, rot, acc);
    stage_epi<6>(acc, h, y, ysr, dh, k1h, k2h, k3h, k4h, k5h, eh, itau4, bias4,
                 A1, wv, l, nullptr);   // act7 -> A1
    __syncthreads();
    gemm8(A1, wfb, l, rot, acc);
    float errAcc = 0.0f;
    stage_epi<7>(acc, h, y, ysr, dh, k1h, k2h, k3h, k4h, k5h, eh, itau4, bias4,
                 nullptr, wv, l, &errAcc);

    // --- block partial + single packed-flag grid exchange (r9-verified) ---
#pragma unroll
    for (int o = 32; o > 0; o >>= 1) errAcc += __shfl_down(errAcc, o, 64);
    if (l == 0) wsum[wv] = errAcc;
    __syncthreads();
    float sblk = 0.0f;
    if (tid == 0) {
#pragma unroll
      for (int w = 0; w < 8; ++w) sblk += wsum[w];
    }
    const u64 ep = (u64)(s + 2);
    const int slot = (int)(ep & 1);
    if (tid == 0)
      AST64(&pk[bid * 8 + slot], (ep << 32) | (u64)__float_as_uint(sblk));
    if (tid < 256) {
      u64 v;
      do { v = ALD64(&pk[tid * 8 + slot]); } while ((v >> 32) < ep);
      sm[tid] = __uint_as_float((unsigned)v);
    }
    __syncthreads();
    if (tid < 64) {
      float a = sm[tid] + sm[tid + 64] + sm[tid + 128] + sm[tid + 192];
#pragma unroll
      for (int o = 1; o < 64; o <<= 1) a += __shfl_xor(a, o, 64);
      if (tid == 0) bc = a;
    }
    __syncthreads();
    float sd = bc;

    // --- controller (uniform in every block) + FSAL commit ---
    float enorm = fmaxf(sqrtf(sd / 2097152.0f), 1e-10f);
    if (enorm <= 1.0f) {
      t = t + h;
#pragma unroll
      for (int e = 0; e < 16; ++e) y[e] = ysr[e];
#pragma unroll
      for (int i = 0; i < 8; ++i) k1h[i] = k2h[i];   // FSAL: k1 = k7
    }
    float factor = fminf(fmaxf(0.9f * powf(enorm, -0.2f), 0.2f), 5.0f);
    dtv = dtv * factor;
  }

  // --- final output ---
#pragma unroll
  for (int ci = 0; ci < 4; ++ci)
#pragma unroll
    for (int q = 0; q < 4; ++q) {
      const int e = ci * 4 + q;
      int row = ((l >> 4) & 1) * 4 + q;
      int col = wv * 128 + ((l >> 5) * 4 + ci) * 16 + lr16;
      out[(size_t)(rbase + row) * 1024 + col] = y[e];
    }
}

extern "C" void kernel_launch(void* const* d_in, const int* in_sizes, int n_in,
                              void* d_out, int out_size, void* d_ws, size_t ws_size,
                              hipStream_t stream) {
  const float* inp = (const float*)d_in[0];
  const float* prev = (const float*)d_in[1];
  const float* tau = (const float*)d_in[2];
  const float* W = (const float*)d_in[3];
  const float* iw = (const float*)d_in[4];
  const float* bias = (const float*)d_in[5];
  float* out = (float*)d_out;

  char* ws = (char*)d_ws;
  u64* pk = (u64*)ws;                          // 16 KB
  _Float16* Wf = (_Float16*)(ws + 64 * 1024);  // 2 MB

  k_zero<<<4, 512, 0, stream>>>(pk);
  k_prep<<<512, 256, 0, stream>>>(W, Wf);
  k_ode<<<NBLK, NTHR, 0, stream>>>(inp, prev, tau, iw, bias, Wf, out, pk);
}

// Round 14
// 659.538 us; speedup vs baseline: 6.7132x; 6.7132x over previous
//
#include <hip/hip_runtime.h>
#include <math.h>

// CTRNN + adaptive DOPRI5 (B=2048, N=1024). Round 14 = r12 GEMM (2-set
// prefetch, per-CU K rotation) + r13 persistence, with register pressure
// fixed: y/ys live in LDS (thread-private slots), B-prefetch hoisted above
// the stage barrier (barrier moved inside gemm8). Block = 8 complete rows;
// act in block-local LDS ping-pong; one packed-flag exchange per step;
// controller redundant+uniform; dead steps = uniform break. FSAL: k1=k7.

typedef float f4 __attribute__((ext_vector_type(4)));
typedef float f32x4 __attribute__((ext_vector_type(4)));
typedef _Float16 half8v __attribute__((ext_vector_type(8)));
typedef _Float16 half2v __attribute__((ext_vector_type(2)));
typedef unsigned long long u64;

#define NBLK 256
#define NTHR 512

#define E1c (71.0f / 57600.0f)
#define E3c (-71.0f / 16695.0f)
#define E4c (71.0f / 1920.0f)
#define E5c (-17253.0f / 339200.0f)
#define E6c (22.0f / 525.0f)
#define E7c (-1.0f / 40.0f)

#define ALD64(p) __hip_atomic_load((p), __ATOMIC_ACQUIRE, __HIP_MEMORY_SCOPE_AGENT)
#define AST64(p, v) __hip_atomic_store((p), (v), __ATOMIC_RELEASE, __HIP_MEMORY_SCOPE_AGENT)

__global__ void k_zero(u64* pk) {
  int i = blockIdx.x * blockDim.x + threadIdx.x;
  if (i < 2048) pk[i] = 0ull;
}

__device__ __forceinline__ float ftanh(float x) {
  x = fminf(fmaxf(x, -9.0f), 9.0f);
  float e = __expf(2.0f * x);
  return (e - 1.0f) / (e + 1.0f);
}

// Wf[((ct16*32 + kb)*64 + l)*8 + j] = W[ct16*16 + (l&15)][kb*32 + (l>>4)*8 + j]
__global__ void k_prep(const float* __restrict__ W, _Float16* __restrict__ Wf) {
  int i = blockIdx.x * blockDim.x + threadIdx.x;   // 0..131071
  int l = i & 63, kb = (i >> 6) & 31, ct = i >> 11;
  const float* src = W + (size_t)(ct * 16 + (l & 15)) * 1024 + kb * 32 + (l >> 4) * 8;
  half8v o;
#pragma unroll
  for (int j = 0; j < 8; ++j) o[j] = (_Float16)src[j];
  *(half8v*)(Wf + ((size_t)i << 3)) = o;
}

// acc[8] = rec fragments for this wave's 8 col-tiles. Contains the stage
// barrier: bA prefetch (global-only) issues first, then __syncthreads
// (act LDS ready), then the pipelined loop. 2-set rotating prefetch (r12).
__device__ __forceinline__ void gemm8(const char* actB,
                                      const _Float16* __restrict__ wfb,
                                      int l, int rot, f32x4 acc[8]) {
#pragma unroll
  for (int ct = 0; ct < 8; ++ct)
#pragma unroll
    for (int q = 0; q < 4; ++q) acc[ct][q] = 0.0f;
  const int r = l & 7, lk = l >> 4;
  const char* arow = actB + r * 2048;
  half8v bA[8], bB[8];
#pragma unroll
  for (int ct = 0; ct < 8; ++ct)
    bA[ct] = *(const half8v*)(wfb + (((ct << 5) + rot) << 9));
  __syncthreads();   // act writes from previous stage visible; bA in flight
#pragma unroll 1
  for (int it = 0; it < 32; it += 2) {
    const int kb0 = (it + rot) & 31;
    const int kb1 = (it + 1 + rot) & 31;
    const int kb2 = (it + 2 + rot) & 31;
    half8v a0 = *(const half8v*)(arow + ((((kb0 << 2) | lk) ^ r) << 4));
#pragma unroll
    for (int ct = 0; ct < 8; ++ct)
      bB[ct] = *(const half8v*)(wfb + (((ct << 5) + kb1) << 9));
#pragma unroll
    for (int ct = 0; ct < 8; ++ct)
      acc[ct] = __builtin_amdgcn_mfma_f32_16x16x32_f16(a0, bA[ct], acc[ct], 0, 0, 0);
    half8v a1 = *(const half8v*)(arow + ((((kb1 << 2) | lk) ^ r) << 4));
#pragma unroll
    for (int ct = 0; ct < 8; ++ct)
      bA[ct] = *(const half8v*)(wfb + (((ct << 5) + kb2) << 9));
#pragma unroll
    for (int ct = 0; ct < 8; ++ct)
      acc[ct] = __builtin_amdgcn_mfma_f32_16x16x32_f16(a1, bB[ct], acc[ct], 0, 0, 0);
  }
}

// e = ci*4 + q. Thread owns rows ((l>>4)&1)*4+q, cols wv*128+((l>>5)*4+ci)*16+(l&15).
// y/ys in LDS (stride-NTHR thread-private slots).
template <int S>
__device__ __forceinline__ void stage_epi(
    const f32x4 acc[8], float h,
    float* yT, float* ysT, const half2v* dh,
    half2v* k1h, half2v* k2h, half2v* k3h, half2v* k4h, half2v* k5h, half2v* eh,
    const float* itau4, const float* bias4,
    char* actOut, int wv, int l, float* errAcc) {
  f32x4 sa[4];
  if (l >= 32) { sa[0] = acc[4]; sa[1] = acc[5]; sa[2] = acc[6]; sa[3] = acc[7]; }
  else         { sa[0] = acc[0]; sa[1] = acc[1]; sa[2] = acc[2]; sa[3] = acc[3]; }
#pragma unroll
  for (int ci = 0; ci < 4; ++ci) {
#pragma unroll
    for (int q = 0; q < 4; ++q) {
      const int e = ci * 4 + q;
      float yv = yT[e * NTHR];
      float ks;
      if constexpr (S == 1) {
        ks = (float)k1h[e >> 1][e & 1];
      } else {
        ks = itau4[ci] * ((float)dh[e >> 1][e & 1] + sa[ci][q] - ysT[e * NTHR]);
      }
      float nys;
      if constexpr (S == 1) {
        eh[e >> 1][e & 1] = (_Float16)(E1c * ks);
        nys = yv + h * (0.2f * ks);
      } else if constexpr (S == 2) {
        k2h[e >> 1][e & 1] = (_Float16)ks;
        float k1 = (float)k1h[e >> 1][e & 1];
        nys = yv + h * ((3.0f / 40.0f) * k1 + (9.0f / 40.0f) * ks);
      } else if constexpr (S == 3) {
        k3h[e >> 1][e & 1] = (_Float16)ks;
        eh[e >> 1][e & 1] = (_Float16)((float)eh[e >> 1][e & 1] + E3c * ks);
        float k1 = (float)k1h[e >> 1][e & 1], k2 = (float)k2h[e >> 1][e & 1];
        nys = yv + h * ((44.0f / 45.0f) * k1 + (-56.0f / 15.0f) * k2 + (32.0f / 9.0f) * ks);
      } else if constexpr (S == 4) {
        k4h[e >> 1][e & 1] = (_Float16)ks;
        eh[e >> 1][e & 1] = (_Float16)((float)eh[e >> 1][e & 1] + E4c * ks);
        float k1 = (float)k1h[e >> 1][e & 1], k2 = (float)k2h[e >> 1][e & 1];
        float k3 = (float)k3h[e >> 1][e & 1];
        nys = yv + h * ((19372.0f / 6561.0f) * k1 + (-25360.0f / 2187.0f) * k2 +
                        (64448.0f / 6561.0f) * k3 + (-212.0f / 729.0f) * ks);
      } else if constexpr (S == 5) {
        k5h[e >> 1][e & 1] = (_Float16)ks;
        eh[e >> 1][e & 1] = (_Float16)((float)eh[e >> 1][e & 1] + E5c * ks);
        float k1 = (float)k1h[e >> 1][e & 1], k2 = (float)k2h[e >> 1][e & 1];
        float k3 = (float)k3h[e >> 1][e & 1], k4 = (float)k4h[e >> 1][e & 1];
        nys = yv + h * ((9017.0f / 3168.0f) * k1 + (-355.0f / 33.0f) * k2 +
                        (46732.0f / 5247.0f) * k3 + (49.0f / 176.0f) * k4 +
                        (-5103.0f / 18656.0f) * ks);
      } else if constexpr (S == 6) {
        eh[e >> 1][e & 1] = (_Float16)((float)eh[e >> 1][e & 1] + E6c * ks);
        float k1 = (float)k1h[e >> 1][e & 1];
        float k3 = (float)k3h[e >> 1][e & 1], k4 = (float)k4h[e >> 1][e & 1];
        float k5 = (float)k5h[e >> 1][e & 1];
        nys = yv + h * ((35.0f / 384.0f) * k1 + (500.0f / 1113.0f) * k3 +
                        (125.0f / 192.0f) * k4 + (-2187.0f / 6784.0f) * k5 +
                        (11.0f / 84.0f) * ks);
      } else {  // S == 7: k7 -> k2h slot (dead after S5); error norm
        k2h[e >> 1][e & 1] = (_Float16)ks;
        float ev = h * ((float)eh[e >> 1][e & 1] + E7c * ks);
        float sc = 1e-6f + 1e-3f * fmaxf(fabsf(yv), fabsf(ysT[e * NTHR]));
        float r = ev / sc;
        *errAcc += r * r;
        nys = 0.0f;
      }
      if constexpr (S <= 6) {
        ysT[e * NTHR] = nys;
        float av = ftanh(nys + bias4[ci]);
        int row = ((l >> 4) & 1) * 4 + q;
        int col = wv * 128 + ((l >> 5) * 4 + ci) * 16 + (l & 15);
        *(_Float16*)(actOut + row * 2048 + (((col >> 3) ^ row) << 4) + (col & 7) * 2) =
            (_Float16)av;
      }
    }
  }
}

__global__ __launch_bounds__(NTHR) void k_ode(
    const float* __restrict__ inp, const float* __restrict__ prev,
    const float* __restrict__ tau, const float* __restrict__ iw,
    const float* __restrict__ bias, const _Float16* __restrict__ Wf,
    float* __restrict__ out, u64* __restrict__ pk) {
  __shared__ _Float16 actL[2][8][1024];   // 32 KB ping-pong act
  __shared__ float yL[16 * NTHR];         // 32 KB y
  __shared__ float ysL[16 * NTHR];        // 32 KB ys
  __shared__ float sm[256];
  __shared__ float wsum[8];
  __shared__ float bc;

  const int tid = (int)threadIdx.x, bid = (int)blockIdx.x;
  const int l = tid & 63, wv = tid >> 6;
  const int lr16 = l & 15;
  const int rbase = bid * 8;
  const int rot = (bid >> 3) & 31;     // per-CU K phase (32 CUs/XCD distinct)
  char* A0 = (char*)&actL[0][0][0];
  char* A1 = (char*)&actL[1][0][0];
  float* yT = yL + tid;
  float* ysT = ysL + tid;
  const _Float16* wfb = Wf + ((size_t)wv << 17) + (l << 3);

  // --- state init + act1 -> A1 ---
  half2v dh[8], k1h[8], k2h[8], k3h[8], k4h[8], k5h[8], eh[8];
  float itau4[4], bias4[4];
#pragma unroll
  for (int ci = 0; ci < 4; ++ci) {
    int col = wv * 128 + ((l >> 5) * 4 + ci) * 16 + lr16;
    itau4[ci] = 1.0f / tau[col];
    bias4[ci] = bias[col];
  }
#pragma unroll
  for (int ci = 0; ci < 4; ++ci)
#pragma unroll
    for (int q = 0; q < 4; ++q) {
      const int e = ci * 4 + q;
      int row = ((l >> 4) & 1) * 4 + q;
      int col = wv * 128 + ((l >> 5) * 4 + ci) * 16 + lr16;
      size_t off = (size_t)(rbase + row) * 1024 + col;
      float yv = prev[off];
      yT[e * NTHR] = yv;
      ysT[e * NTHR] = yv;
      dh[e >> 1][e & 1] = (_Float16)(inp[off] * iw[col]);
      float av = ftanh(yv + bias4[ci]);
      *(_Float16*)(A1 + row * 2048 + (((col >> 3) ^ row) << 4) + (col & 7) * 2) =
          (_Float16)av;
    }

  // initial k1 = itau*(drive + W@act1 - y)  (gemm8 contains the barrier)
  f32x4 acc[8];
  gemm8(A1, wfb, l, rot, acc);
  {
    f32x4 sa[4];
    if (l >= 32) { sa[0] = acc[4]; sa[1] = acc[5]; sa[2] = acc[6]; sa[3] = acc[7]; }
    else         { sa[0] = acc[0]; sa[1] = acc[1]; sa[2] = acc[2]; sa[3] = acc[3]; }
#pragma unroll
    for (int ci = 0; ci < 4; ++ci)
#pragma unroll
      for (int q = 0; q < 4; ++q) {
        const int e = ci * 4 + q;
        k1h[e >> 1][e & 1] =
            (_Float16)(itau4[ci] * ((float)dh[e >> 1][e & 1] + sa[ci][q] - yT[e * NTHR]));
      }
  }

  float t = 0.0f, dtv = 0.1f;
#pragma unroll 1
  for (int s = 0; s < 40; ++s) {
    if (t >= 1.0f - 1e-7f) break;
    const float h = fminf(dtv, 1.0f - t);

    stage_epi<1>(acc, h, yT, ysT, dh, k1h, k2h, k3h, k4h, k5h, eh, itau4, bias4,
                 A0, wv, l, nullptr);
    gemm8(A0, wfb, l, rot, acc);
    stage_epi<2>(acc, h, yT, ysT, dh, k1h, k2h, k3h, k4h, k5h, eh, itau4, bias4,
                 A1, wv, l, nullptr);
    gemm8(A1, wfb, l, rot, acc);
    stage_epi<3>(acc, h, yT, ysT, dh, k1h, k2h, k3h, k4h, k5h, eh, itau4, bias4,
                 A0, wv, l, nullptr);
    gemm8(A0, wfb, l, rot, acc);
    stage_epi<4>(acc, h, yT, ysT, dh, k1h, k2h, k3h, k4h, k5h, eh, itau4, bias4,
                 A1, wv, l, nullptr);
    gemm8(A1, wfb, l, rot, acc);
    stage_epi<5>(acc, h, yT, ysT, dh, k1h, k2h, k3h, k4h, k5h, eh, itau4, bias4,
                 A0, wv, l, nullptr);
    gemm8(A0, wfb, l, rot, acc);
    stage_epi<6>(acc, h, yT, ysT, dh, k1h, k2h, k3h, k4h, k5h, eh, itau4, bias4,
                 A1, wv, l, nullptr);   // act7 -> A1
    gemm8(A1, wfb, l, rot, acc);
    float errAcc = 0.0f;
    stage_epi<7>(acc, h, yT, ysT, dh, k1h, k2h, k3h, k4h, k5h, eh, itau4, bias4,
                 nullptr, wv, l, &errAcc);

    // --- block partial + single packed-flag grid exchange (r9-verified) ---
#pragma unroll
    for (int o = 32; o > 0; o >>= 1) errAcc += __shfl_down(errAcc, o, 64);
    if (l == 0) wsum[wv] = errAcc;
    __syncthreads();
    float sblk = 0.0f;
    if (tid == 0) {
#pragma unroll
      for (int w = 0; w < 8; ++w) sblk += wsum[w];
    }
    const u64 ep = (u64)(s + 2);
    const int slot = (int)(ep & 1);
    if (tid == 0)
      AST64(&pk[bid * 8 + slot], (ep << 32) | (u64)__float_as_uint(sblk));
    if (tid < 256) {
      u64 v;
      do { v = ALD64(&pk[tid * 8 + slot]); } while ((v >> 32) < ep);
      sm[tid] = __uint_as_float((unsigned)v);
    }
    __syncthreads();
    if (tid < 64) {
      float a = sm[tid] + sm[tid + 64] + sm[tid + 128] + sm[tid + 192];
#pragma unroll
      for (int o = 1; o < 64; o <<= 1) a += __shfl_xor(a, o, 64);
      if (tid == 0) bc = a;
    }
    __syncthreads();
    float sd = bc;

    // --- controller (uniform in every block) + FSAL commit ---
    float enorm = fmaxf(sqrtf(sd / 2097152.0f), 1e-10f);
    if (enorm <= 1.0f) {
      t = t + h;
#pragma unroll
      for (int e = 0; e < 16; ++e) yT[e * NTHR] = ysT[e * NTHR];
#pragma unroll
      for (int i = 0; i < 8; ++i) k1h[i] = k2h[i];   // FSAL: k1 = k7
    }
    float factor = fminf(fmaxf(0.9f * powf(enorm, -0.2f), 0.2f), 5.0f);
    dtv = dtv * factor;
  }

  // --- final output ---
#pragma unroll
  for (int ci = 0; ci < 4; ++ci)
#pragma unroll
    for (int q = 0; q < 4; ++q) {
      const int e = ci * 4 + q;
      int row = ((l >> 4) & 1) * 4 + q;
      int col = wv * 128 + ((l >> 5) * 4 + ci) * 16 + lr16;
      out[(size_t)(rbase + row) * 1024 + col] = yT[e * NTHR];
    }
}

extern "C" void kernel_launch(void* const* d_in, const int* in_sizes, int n_in,
                              void* d_out, int out_size, void* d_ws, size_t ws_size,
                              hipStream_t stream) {
  const float* inp = (const float*)d_in[0];
  const float* prev = (const float*)d_in[1];
  const float* tau = (const float*)d_in[2];
  const float* W = (const float*)d_in[3];
  const float* iw = (const float*)d_in[4];
  const float* bias = (const float*)d_in[5];
  float* out = (float*)d_out;

  char* ws = (char*)d_ws;
  u64* pk = (u64*)ws;                          // 16 KB
  _Float16* Wf = (_Float16*)(ws + 64 * 1024);  // 2 MB

  k_zero<<<4, 512, 0, stream>>>(pk);
  k_prep<<<512, 256, 0, stream>>>(W, Wf);
  k_ode<<<NBLK, NTHR, 0, stream>>>(inp, prev, tau, iw, bias, Wf, out, pk);
}

// Round 15
// 584.506 us; speedup vs baseline: 7.5749x; 1.1284x over previous
//
#include <hip/hip_runtime.h>
#include <math.h>

// CTRNN + adaptive DOPRI5 (B=2048, N=1024). Round 15 = r14 + col-split:
// 256 blocks = 128 rowgroups(16 rows) x 2 col-halves(512 cols). M=16 ->
// no MFMA row duplication; B traffic per GEMM halves to 1 MB/block.
// Per stage: epilogue writes own swizzled act half-image (LDS) -> coalesced
// copy to gx -> pair flag release -> own-K-half GEMM (overlaps partner) ->
// acquire -> global_load_lds 16KB partner image -> partner-K-half GEMM.
// Partner = bid^8 (same XCD). Persistent kernel; y/ys in LDS; k's in half2
// regs; single packed-flag err exchange per step; FSAL k1=k7.

typedef float f4 __attribute__((ext_vector_type(4)));
typedef float f32x4 __attribute__((ext_vector_type(4)));
typedef _Float16 half8v __attribute__((ext_vector_type(8)));
typedef _Float16 half2v __attribute__((ext_vector_type(2)));
typedef unsigned long long u64;

#define AS1 __attribute__((address_space(1)))
#define AS3 __attribute__((address_space(3)))

#define NBLK 256
#define NTHR 512

#define E1c (71.0f / 57600.0f)
#define E3c (-71.0f / 16695.0f)
#define E4c (71.0f / 1920.0f)
#define E5c (-17253.0f / 339200.0f)
#define E6c (22.0f / 525.0f)
#define E7c (-1.0f / 40.0f)

#define ALDI(p) __hip_atomic_load((p), __ATOMIC_ACQUIRE, __HIP_MEMORY_SCOPE_AGENT)
#define ASTI(p, v) __hip_atomic_store((p), (v), __ATOMIC_RELEASE, __HIP_MEMORY_SCOPE_AGENT)
#define ALD64(p) __hip_atomic_load((p), __ATOMIC_ACQUIRE, __HIP_MEMORY_SCOPE_AGENT)
#define AST64(p, v) __hip_atomic_store((p), (v), __ATOMIC_RELEASE, __HIP_MEMORY_SCOPE_AGENT)

__global__ void k_zero(u64* pk, int* flg) {
  int i = blockIdx.x * blockDim.x + threadIdx.x;
  if (i < 2048) pk[i] = 0ull;
  if (i < 4096) flg[i] = 0;
}

__device__ __forceinline__ float ftanh(float x) {
  x = fminf(fmaxf(x, -9.0f), 9.0f);
  float e = __expf(2.0f * x);
  return (e - 1.0f) / (e + 1.0f);
}

// Wf[((ct16*32 + kb)*64 + l)*8 + j] = W[ct16*16 + (l&15)][kb*32 + (l>>4)*8 + j]
__global__ void k_prep(const float* __restrict__ W, _Float16* __restrict__ Wf) {
  int i = blockIdx.x * blockDim.x + threadIdx.x;   // 0..131071
  int l = i & 63, kb = (i >> 6) & 31, ct = i >> 11;
  const float* src = W + (size_t)(ct * 16 + (l & 15)) * 1024 + kb * 32 + (l >> 4) * 8;
  half8v o;
#pragma unroll
  for (int j = 0; j < 8; ++j) o[j] = (_Float16)src[j];
  *(half8v*)(Wf + ((size_t)i << 3)) = o;
}

__device__ __forceinline__ f32x4 mfma(half8v a, half8v b, f32x4 c) {
  return __builtin_amdgcn_mfma_f32_16x16x32_f16(a, b, c, 0, 0, 0);
}

// One K-half (512) of rec[16 x (4 ct)] for this wave. A from swizzled LDS
// half-image; B from fragment-contiguous Wf (wfk pre-offset to the K-half).
// 2-set rotating register prefetch + per-CU K rotation.
__device__ __forceinline__ void gemm_half(const char* Ak, const _Float16* wfk,
                                          int l, int rot, f32x4 acc[4]) {
  const int r = l & 15, lk = l >> 4, r7 = l & 7;
  const char* arow = Ak + r * 1024;
  half8v bA[4], bB[4];
#pragma unroll
  for (int ci = 0; ci < 4; ++ci)
    bA[ci] = *(const half8v*)(wfk + (ci << 14) + (rot << 9));
#pragma unroll 1
  for (int it = 0; it < 16; it += 2) {
    const int kb0 = (it + rot) & 15;
    const int kb1 = (it + 1 + rot) & 15;
    const int kb2 = (it + 2 + rot) & 15;
    half8v a0 = *(const half8v*)(arow + ((((kb0 << 2) | lk) ^ r7) << 4));
#pragma unroll
    for (int ci = 0; ci < 4; ++ci)
      bB[ci] = *(const half8v*)(wfk + (ci << 14) + (kb1 << 9));
#pragma unroll
    for (int ci = 0; ci < 4; ++ci) acc[ci] = mfma(a0, bA[ci], acc[ci]);
    half8v a1 = *(const half8v*)(arow + ((((kb1 << 2) | lk) ^ r7) << 4));
#pragma unroll
    for (int ci = 0; ci < 4; ++ci)
      bA[ci] = *(const half8v*)(wfk + (ci << 14) + (kb2 << 9));
#pragma unroll
    for (int ci = 0; ci < 4; ++ci) acc[ci] = mfma(a1, bB[ci], acc[ci]);
  }
}

// act-exchange + both GEMM halves. Ab = LDS act buffer (2 half-images).
__device__ __forceinline__ void exch_gemm(
    char* Ab, _Float16* gxm, const _Float16* gxp,
    int* flg, int bid, int partner, int pcnt,
    const _Float16* wfbW, int colHalf, int l, int tid, int rot, f32x4 acc[4]) {
  __syncthreads();   // epilogue act writes visible block-wide
  {
    const char* src = Ab + colHalf * 16384;
    char* dst = (char*)gxm;
#pragma unroll
    for (int u = 0; u < 2; ++u) {
      int off = (u * 512 + tid) * 16;
      f4 v = *(const f4*)(src + off);
      *(f4*)(dst + off) = v;
    }
  }
  __syncthreads();   // copy stores drained (vmcnt0 before barrier)
  if (tid == 0) ASTI(&flg[bid * 16], pcnt);
#pragma unroll
  for (int ci = 0; ci < 4; ++ci)
#pragma unroll
    for (int q = 0; q < 4; ++q) acc[ci][q] = 0.0f;
  gemm_half(Ab + colHalf * 16384, wfbW + (colHalf << 13), l, rot, acc);
  if (tid == 0) {
    while (ALDI(&flg[partner * 16]) < pcnt) __builtin_amdgcn_s_sleep(1);
  }
  __syncthreads();
#pragma unroll
  for (int u = 0; u < 2; ++u) {
    int off = (u * 512 + tid) * 16;
    __builtin_amdgcn_global_load_lds(
        (const AS1 void*)((const char*)gxp + off),
        (AS3 void*)(Ab + (colHalf ^ 1) * 16384 + off), 16, 0, 0);
  }
  __syncthreads();   // staging drained
  gemm_half(Ab + (colHalf ^ 1) * 16384, wfbW + ((colHalf ^ 1) << 13), l, rot, acc);
}

// e = ci*4 + q. Thread: rows lk4+q (0..15 local), col = colHalf*512 + wv*64
// + ci*16 + (l&15). y/ys in LDS thread-private slots.
template <int S>
__device__ __forceinline__ void stage_epi(
    const f32x4 acc[4], float h,
    float* yT, float* ysT, const half2v* dh,
    half2v* k1h, half2v* k2h, half2v* k3h, half2v* k4h, half2v* k5h, half2v* eh,
    const float* itau4, const float* bias4,
    char* Ab, int colHalf, int wv, int l, float* errAcc) {
  const int lk4 = (l >> 4) * 4, lr16 = l & 15;
#pragma unroll
  for (int ci = 0; ci < 4; ++ci) {
#pragma unroll
    for (int q = 0; q < 4; ++q) {
      const int e = ci * 4 + q;
      float yv = yT[e * NTHR];
      float ks;
      if constexpr (S == 1) {
        ks = (float)k1h[e >> 1][e & 1];
      } else {
        ks = itau4[ci] * ((float)dh[e >> 1][e & 1] + acc[ci][q] - ysT[e * NTHR]);
      }
      float nys;
      if constexpr (S == 1) {
        eh[e >> 1][e & 1] = (_Float16)(E1c * ks);
        nys = yv + h * (0.2f * ks);
      } else if constexpr (S == 2) {
        k2h[e >> 1][e & 1] = (_Float16)ks;
        float k1 = (float)k1h[e >> 1][e & 1];
        nys = yv + h * ((3.0f / 40.0f) * k1 + (9.0f / 40.0f) * ks);
      } else if constexpr (S == 3) {
        k3h[e >> 1][e & 1] = (_Float16)ks;
        eh[e >> 1][e & 1] = (_Float16)((float)eh[e >> 1][e & 1] + E3c * ks);
        float k1 = (float)k1h[e >> 1][e & 1], k2 = (float)k2h[e >> 1][e & 1];
        nys = yv + h * ((44.0f / 45.0f) * k1 + (-56.0f / 15.0f) * k2 + (32.0f / 9.0f) * ks);
      } else if constexpr (S == 4) {
        k4h[e >> 1][e & 1] = (_Float16)ks;
        eh[e >> 1][e & 1] = (_Float16)((float)eh[e >> 1][e & 1] + E4c * ks);
        float k1 = (float)k1h[e >> 1][e & 1], k2 = (float)k2h[e >> 1][e & 1];
        float k3 = (float)k3h[e >> 1][e & 1];
        nys = yv + h * ((19372.0f / 6561.0f) * k1 + (-25360.0f / 2187.0f) * k2 +
                        (64448.0f / 6561.0f) * k3 + (-212.0f / 729.0f) * ks);
      } else if constexpr (S == 5) {
        k5h[e >> 1][e & 1] = (_Float16)ks;
        eh[e >> 1][e & 1] = (_Float16)((float)eh[e >> 1][e & 1] + E5c * ks);
        float k1 = (float)k1h[e >> 1][e & 1], k2 = (float)k2h[e >> 1][e & 1];
        float k3 = (float)k3h[e >> 1][e & 1], k4 = (float)k4h[e >> 1][e & 1];
        nys = yv + h * ((9017.0f / 3168.0f) * k1 + (-355.0f / 33.0f) * k2 +
                        (46732.0f / 5247.0f) * k3 + (49.0f / 176.0f) * k4 +
                        (-5103.0f / 18656.0f) * ks);
      } else if constexpr (S == 6) {
        eh[e >> 1][e & 1] = (_Float16)((float)eh[e >> 1][e & 1] + E6c * ks);
        float k1 = (float)k1h[e >> 1][e & 1];
        float k3 = (float)k3h[e >> 1][e & 1], k4 = (float)k4h[e >> 1][e & 1];
        float k5 = (float)k5h[e >> 1][e & 1];
        nys = yv + h * ((35.0f / 384.0f) * k1 + (500.0f / 1113.0f) * k3 +
                        (125.0f / 192.0f) * k4 + (-2187.0f / 6784.0f) * k5 +
                        (11.0f / 84.0f) * ks);
      } else {  // S == 7: k7 -> k2h slot (dead after S5); error norm
        k2h[e >> 1][e & 1] = (_Float16)ks;
        float ev = h * ((float)eh[e >> 1][e & 1] + E7c * ks);
        float sc = 1e-6f + 1e-3f * fmaxf(fabsf(yv), fabsf(ysT[e * NTHR]));
        float r = ev / sc;
        *errAcc += r * r;
        nys = 0.0f;
      }
      if constexpr (S <= 6) {
        ysT[e * NTHR] = nys;
        float av = ftanh(nys + bias4[ci]);
        int rowl = lk4 + q;
        int colp = wv * 64 + ci * 16 + lr16;
        *(_Float16*)(Ab + colHalf * 16384 + rowl * 1024 +
                     ((((colp >> 3) ^ (rowl & 7)) << 4)) + (colp & 7) * 2) =
            (_Float16)av;
      }
    }
  }
}

__global__ __launch_bounds__(NTHR) void k_ode(
    const float* __restrict__ inp, const float* __restrict__ prev,
    const float* __restrict__ tau, const float* __restrict__ iw,
    const float* __restrict__ bias, const _Float16* __restrict__ Wf,
    _Float16* __restrict__ gx, float* __restrict__ out,
    u64* __restrict__ pk, int* __restrict__ flg) {
  __shared__ _Float16 actL[2][2][16][512];   // 64 KB: 2 buf x 2 half-image
  __shared__ float yL[16 * NTHR];            // 32 KB
  __shared__ float ysL[16 * NTHR];           // 32 KB
  __shared__ float sm[256];
  __shared__ float wsum[8];
  __shared__ float bc;

  const int tid = (int)threadIdx.x, bid = (int)blockIdx.x;
  const int l = tid & 63, wv = tid >> 6;
  const int lr16 = l & 15, lk4 = (l >> 4) * 4;
  const int rowGroup = (bid & 7) | ((bid >> 4) << 3);   // 0..127
  const int colHalf = (bid >> 3) & 1;
  const int partner = bid ^ 8;                          // same XCD
  const int rbase = rowGroup * 16;
  const int rot = (bid >> 3) & 15;
  char* A0 = (char*)&actL[0][0][0][0];
  char* A1 = (char*)&actL[1][0][0][0];
  float* yT = yL + tid;
  float* ysT = ysL + tid;
  const _Float16* wfbW = Wf + ((size_t)(colHalf * 32 + wv * 4) << 14) + (l << 3);
  _Float16* gxm[2];
  const _Float16* gxp[2];
#pragma unroll
  for (int b = 0; b < 2; ++b) {
    gxm[b] = gx + (size_t)(b * 256 + bid) * 8192;
    gxp[b] = gx + (size_t)(b * 256 + partner) * 8192;
  }

  // --- state init + act1 own half -> A1 ---
  half2v dh[8], k1h[8], k2h[8], k3h[8], k4h[8], k5h[8], eh[8];
  float itau4[4], bias4[4];
#pragma unroll
  for (int ci = 0; ci < 4; ++ci) {
    int col = colHalf * 512 + wv * 64 + ci * 16 + lr16;
    itau4[ci] = 1.0f / tau[col];
    bias4[ci] = bias[col];
  }
#pragma unroll
  for (int ci = 0; ci < 4; ++ci)
#pragma unroll
    for (int q = 0; q < 4; ++q) {
      const int e = ci * 4 + q;
      int rowl = lk4 + q;
      int colp = wv * 64 + ci * 16 + lr16;
      int col = colHalf * 512 + colp;
      size_t off = (size_t)(rbase + rowl) * 1024 + col;
      float yv = prev[off];
      yT[e * NTHR] = yv;
      ysT[e * NTHR] = yv;
      dh[e >> 1][e & 1] = (_Float16)(inp[off] * iw[col]);
      float av = ftanh(yv + bias4[ci]);
      *(_Float16*)(A1 + colHalf * 16384 + rowl * 1024 +
                   ((((colp >> 3) ^ (rowl & 7)) << 4)) + (colp & 7) * 2) =
          (_Float16)av;
    }

  // --- initial k1 (exchange epoch 1, buf 1) ---
  f32x4 acc[4];
  int pcnt = 1;
  exch_gemm(A1, gxm[1], gxp[1], flg, bid, partner, pcnt,
            wfbW, colHalf, l, tid, rot, acc);
#pragma unroll
  for (int ci = 0; ci < 4; ++ci)
#pragma unroll
    for (int q = 0; q < 4; ++q) {
      const int e = ci * 4 + q;
      k1h[e >> 1][e & 1] =
          (_Float16)(itau4[ci] * ((float)dh[e >> 1][e & 1] + acc[ci][q] - yT[e * NTHR]));
    }

  float t = 0.0f, dtv = 0.1f;
#pragma unroll 1
  for (int s = 0; s < 40; ++s) {
    if (t >= 1.0f - 1e-7f) break;
    const float h = fminf(dtv, 1.0f - t);

    stage_epi<1>(acc, h, yT, ysT, dh, k1h, k2h, k3h, k4h, k5h, eh, itau4, bias4,
                 A0, colHalf, wv, l, nullptr);
    exch_gemm(A0, gxm[0], gxp[0], flg, bid, partner, ++pcnt,
              wfbW, colHalf, l, tid, rot, acc);
    stage_epi<2>(acc, h, yT, ysT, dh, k1h, k2h, k3h, k4h, k5h, eh, itau4, bias4,
                 A1, colHalf, wv, l, nullptr);
    exch_gemm(A1, gxm[1], gxp[1], flg, bid, partner, ++pcnt,
              wfbW, colHalf, l, tid, rot, acc);
    stage_epi<3>(acc, h, yT, ysT, dh, k1h, k2h, k3h, k4h, k5h, eh, itau4, bias4,
                 A0, colHalf, wv, l, nullptr);
    exch_gemm(A0, gxm[0], gxp[0], flg, bid, partner, ++pcnt,
              wfbW, colHalf, l, tid, rot, acc);
    stage_epi<4>(acc, h, yT, ysT, dh, k1h, k2h, k3h, k4h, k5h, eh, itau4, bias4,
                 A1, colHalf, wv, l, nullptr);
    exch_gemm(A1, gxm[1], gxp[1], flg, bid, partner, ++pcnt,
              wfbW, colHalf, l, tid, rot, acc);
    stage_epi<5>(acc, h, yT, ysT, dh, k1h, k2h, k3h, k4h, k5h, eh, itau4, bias4,
                 A0, colHalf, wv, l, nullptr);
    exch_gemm(A0, gxm[0], gxp[0], flg, bid, partner, ++pcnt,
              wfbW, colHalf, l, tid, rot, acc);
    stage_epi<6>(acc, h, yT, ysT, dh, k1h, k2h, k3h, k4h, k5h, eh, itau4, bias4,
                 A1, colHalf, wv, l, nullptr);   // act7 -> buf1
    exch_gemm(A1, gxm[1], gxp[1], flg, bid, partner, ++pcnt,
              wfbW, colHalf, l, tid, rot, acc);
    float errAcc = 0.0f;
    stage_epi<7>(acc, h, yT, ysT, dh, k1h, k2h, k3h, k4h, k5h, eh, itau4, bias4,
                 nullptr, colHalf, wv, l, &errAcc);

    // --- block partial + single packed-flag grid exchange (r9-verified) ---
#pragma unroll
    for (int o = 32; o > 0; o >>= 1) errAcc += __shfl_down(errAcc, o, 64);
    if (l == 0) wsum[wv] = errAcc;
    __syncthreads();
    float sblk = 0.0f;
    if (tid == 0) {
#pragma unroll
      for (int w = 0; w < 8; ++w) sblk += wsum[w];
    }
    const u64 ep = (u64)(s + 2);
    const int slot = (int)(ep & 1);
    if (tid == 0)
      AST64(&pk[bid * 8 + slot], (ep << 32) | (u64)__float_as_uint(sblk));
    if (tid < 256) {
      u64 v;
      do { v = ALD64(&pk[tid * 8 + slot]); } while ((v >> 32) < ep);
      sm[tid] = __uint_as_float((unsigned)v);
    }
    __syncthreads();
    if (tid < 64) {
      float a = sm[tid] + sm[tid + 64] + sm[tid + 128] + sm[tid + 192];
#pragma unroll
      for (int o = 1; o < 64; o <<= 1) a += __shfl_xor(a, o, 64);
      if (tid == 0) bc = a;
    }
    __syncthreads();
    float sd = bc;

    // --- controller (uniform in every block) + FSAL commit ---
    float enorm = fmaxf(sqrtf(sd / 2097152.0f), 1e-10f);
    if (enorm <= 1.0f) {
      t = t + h;
#pragma unroll
      for (int e = 0; e < 16; ++e) yT[e * NTHR] = ysT[e * NTHR];
#pragma unroll
      for (int i = 0; i < 8; ++i) k1h[i] = k2h[i];   // FSAL: k1 = k7
    }
    float factor = fminf(fmaxf(0.9f * powf(enorm, -0.2f), 0.2f), 5.0f);
    dtv = dtv * factor;
  }

  // --- final output ---
#pragma unroll
  for (int ci = 0; ci < 4; ++ci)
#pragma unroll
    for (int q = 0; q < 4; ++q) {
      const int e = ci * 4 + q;
      int rowl = lk4 + q;
      int col = colHalf * 512 + wv * 64 + ci * 16 + lr16;
      out[(size_t)(rbase + rowl) * 1024 + col] = yT[e * NTHR];
    }
}

extern "C" void kernel_launch(void* const* d_in, const int* in_sizes, int n_in,
                              void* d_out, int out_size, void* d_ws, size_t ws_size,
                              hipStream_t stream) {
  const float* inp = (const float*)d_in[0];
  const float* prev = (const float*)d_in[1];
  const float* tau = (const float*)d_in[2];
  const float* W = (const float*)d_in[3];
  const float* iw = (const float*)d_in[4];
  const float* bias = (const float*)d_in[5];
  float* out = (float*)d_out;

  char* ws = (char*)d_ws;
  const size_t MB = 1024 * 1024;
  u64* pk = (u64*)ws;                          // 16 KB
  int* flg = (int*)(ws + 16384);               // 16 KB
  _Float16* Wf = (_Float16*)(ws + 64 * 1024);  // 2 MB
  _Float16* gx = (_Float16*)(ws + 64 * 1024 + 2 * MB);  // 8 MB (2 buf x 256 x 16KB)

  k_zero<<<8, 512, 0, stream>>>(pk, flg);
  k_prep<<<512, 256, 0, stream>>>(W, Wf);
  k_ode<<<NBLK, NTHR, 0, stream>>>(inp, prev, tau, iw, bias, Wf, gx, out, pk, flg);
}